// Round 6
// baseline (418.391 us; speedup 1.0000x reference)
//
#include <hip/hip_runtime.h>
#include <hip/hip_bf16.h>
#include <stdint.h>

// ---------------------------------------------------------------------------
// FacebookAdaptiveSoftmax forward on MI355X (gfx950) — R6
//   out[4096, 50259] = concat(x@head_w^T, (x@t0w1^T)@t0w2^T * m0, (x@t1w1^T)@t1w2^T * m1)
//   new_head_target[4096] appended flat (as float)
// R6 changes vs R5:
//   * gemm8: proper (row&7)<<4 LDS XOR-swizzle (was 2-way -> 8-way bank
//     conflicts on ds_read_b128; now conflict-free, T2 recipe) applied on
//     BOTH gload source slots and ds_read addresses (same involution).
//   * zero-fill of masked tail rows moved INTO the gemm8 launch epilogue
//     (blocks fill slices after their GEMM -> overlaps head compute,
//     soaks idle write BW). L1 is casts only.
// ---------------------------------------------------------------------------

typedef float  f32x4   __attribute__((ext_vector_type(4)));
typedef short  short8  __attribute__((ext_vector_type(8)));
typedef unsigned short ushort8 __attribute__((ext_vector_type(8)));

#define CUT0 10000
#define CUT1 40000
#define CUT2 50257
#define LDC   50259L

__device__ __forceinline__ void gload16(const void* g, void* l) {
    __builtin_amdgcn_global_load_lds(
        (__attribute__((address_space(1))) void*)(g),
        (__attribute__((address_space(3))) void*)(l), 16, 0, 0);
}

__device__ __forceinline__ unsigned short f2bf(float f) {
    unsigned int u = __float_as_uint(f);
    u += 0x7fffu + ((u >> 16) & 1u);   // round-to-nearest-even
    return (unsigned short)(u >> 16);
}

__device__ __forceinline__ short8 dsr128(unsigned addr) {
    f32x4 r;
    asm volatile("ds_read_b128 %0, %1" : "=v"(r) : "v"(addr));
    return __builtin_bit_cast(short8, r);
}

__device__ __forceinline__ f32x4 mfma16(short8 a, short8 b, f32x4 c) {
    return __builtin_amdgcn_mfma_f32_16x16x32_bf16(a, b, c, 0, 0, 0);
}

// ===========================================================================
// L0: target remap + order-preserving compaction scan (1 block, 1024 thr).
// ===========================================================================
__global__ __launch_bounds__(1024)
void scan_kernel(const int* __restrict__ tgt, float* __restrict__ outT,
                 int* __restrict__ in0, int* __restrict__ z0,
                 int* __restrict__ in1, int* __restrict__ z1,
                 int* __restrict__ cnts) {
    __shared__ int w0[16], w1[16];
    const int t = threadIdx.x;
    int f0[4], f1[4];
    int c0 = 0, c1 = 0;
#pragma unroll
    for (int j = 0; j < 4; ++j) {
        const int r = t * 4 + j;
        const int v = tgt[r];
        const int b0 = (v >= CUT0) && (v < CUT1);
        const int b1 = (v >= CUT1) && (v < CUT2);
        f0[j] = b0; f1[j] = b1;
        c0 += b0; c1 += b1;
        outT[r] = (float)(b0 ? CUT0 : (b1 ? CUT0 + 1 : v));
    }
    const int lane = t & 63, w = t >> 6;
    int s0 = c0, s1 = c1;
    for (int d = 1; d < 64; d <<= 1) {
        const int u0 = __shfl_up(s0, d, 64);
        const int u1 = __shfl_up(s1, d, 64);
        if (lane >= d) { s0 += u0; s1 += u1; }
    }
    if (lane == 63) { w0[w] = s0; w1[w] = s1; }
    __syncthreads();
    if (t == 0) {
        int a0 = 0, a1 = 0;
        for (int i = 0; i < 16; ++i) {
            const int x0 = w0[i]; w0[i] = a0; a0 += x0;
            const int x1 = w1[i]; w1[i] = a1; a1 += x1;
        }
        cnts[0] = a0; cnts[1] = a1;
    }
    __syncthreads();
    int run0 = w0[w] + (s0 - c0);
    int run1 = w1[w] + (s1 - c1);
#pragma unroll
    for (int j = 0; j < 4; ++j) {
        const int r = t * 4 + j;
        if (f0[j]) in0[run0++] = r; else z0[r - run0] = r;
        if (f1[j]) in1[run1++] = r; else z1[r - run1] = r;
    }
}

// ===========================================================================
// L1: fused casts only (5 segments, f32 -> bf16, zero row padding).
// ===========================================================================
struct CastSeg {
    const float* srcA;
    const float* srcB;
    unsigned short* dst;
    long rowsA, rowsB, total8;
    int lk, pad;
};
struct CastArgs {
    CastSeg s[5];
    long grand8;
};

__global__ __launch_bounds__(256)
void cast_kernel(CastArgs a) {
    long i = blockIdx.x * 256L + threadIdx.x;
    const long stride = (long)gridDim.x * 256L;
    for (; i < a.grand8; i += stride) {
        long off = i;
        int s = 0;
        while (s < 4 && off >= a.s[s].total8) { off -= a.s[s].total8; s++; }
        const CastSeg& sg = a.s[s];
        const long e   = off << 3;
        const long row = e >> sg.lk;
        ushort8 o;
        const float* src = nullptr;
        long r2 = row;
        if (row < sg.rowsA)      src = sg.srcA;
        else if (row < sg.rowsB) { src = sg.srcB; r2 = row - sg.rowsA; }
        if (src) {
            const long col = e & ((1L << sg.lk) - 1);
            const float* p = src + (r2 << sg.lk) + col;
            const float4 v0 = *(const float4*)(p);
            const float4 v1 = *(const float4*)(p + 4);
            o[0] = f2bf(v0.x); o[1] = f2bf(v0.y); o[2] = f2bf(v0.z); o[3] = f2bf(v0.w);
            o[4] = f2bf(v1.x); o[5] = f2bf(v1.y); o[6] = f2bf(v1.z); o[7] = f2bf(v1.w);
        } else {
            o = (ushort8)0;
        }
        *(ushort8*)(sg.dst + e) = o;
    }
}

// ===========================================================================
// L2: 8-phase 256x256 BK=64 GEMM, dual-config (head f32-out | h01 bf16-out),
// with proper (row&7)<<4 LDS swizzle, plus zero-fill of masked tail rows in
// the epilogue (overlaps other blocks' compute).
// ===========================================================================
#define STAGE2(MATP, LDM, RB, KCOL, LOFF)                                          \
    do {                                                                           \
        const unsigned short* _s0 = (MATP) + ((long)((RB) + (tid >> 3))) * (LDM) + (KCOL); \
        gload16(_s0, smem + (LOFF) + wave * 1024);                                 \
        const unsigned short* _s1 = (MATP) + ((long)((RB) + 64 + (tid >> 3))) * (LDM) + (KCOL); \
        gload16(_s1, smem + (LOFF) + 8192 + wave * 1024);                          \
    } while (0)

__global__ __launch_bounds__(512, 2)
void gemm8_dual_kernel(const unsigned short* __restrict__ A0,
                       const unsigned short* __restrict__ B0,
                       float* __restrict__ C0,
                       int nkt0, int lda0, int ldb0, int width0, int NB0, int nblk0,
                       const unsigned short* __restrict__ A1,
                       const unsigned short* __restrict__ B1,
                       unsigned short* __restrict__ C1,
                       int nkt1, int lda1, int ldb1, long ldc1, int width1, int NB1,
                       const int* __restrict__ z0, const int* __restrict__ z1,
                       const int* __restrict__ cnts, float* __restrict__ outFull) {
    __shared__ char smem[131072];

    const int tid  = threadIdx.x;
    const int lane = tid & 63;
    const int wave = tid >> 6;
    const int wr   = wave >> 2;
    const int wc   = wave & 3;

    const bool isHead = (int)blockIdx.x < nblk0;
    const unsigned short* A = isHead ? A0 : A1;
    const unsigned short* B = isHead ? B0 : B1;
    const int nkt   = isHead ? nkt0 : nkt1;
    const int lda   = isHead ? lda0 : lda1;
    const int ldb   = isHead ? ldb0 : ldb1;
    const int width = isHead ? width0 : width1;
    const int NB    = isHead ? NB0 : NB1;
    const int lbid  = isHead ? blockIdx.x : blockIdx.x - nblk0;
    const int nwg   = isHead ? nblk0 : (int)gridDim.x - nblk0;

    const int q = nwg >> 3, r = nwg & 7;
    const int xcd = lbid & 7, loc = lbid >> 3;
    const int L = (xcd < r ? xcd * (q + 1) : r * (q + 1) + (xcd - r) * q) + loc;
    const int g = L / (NB * 4);
    const int t = L - g * (NB * 4);
    const long bm = g * 4 + (t & 3);
    const long bn = t >> 2;

    const long bmRow = bm * 256;
    const long bnRow = bn * 256;

    // staging source slot pre-swizzled by row&7: slot_src = (tid&7) ^ (row&7)
    const int scol = (((tid & 7) ^ ((tid >> 3) & 7)) << 3);

    // ds_read addresses: byte col = kbyte ^ ((row&7)<<4), row = lane&15
    const unsigned lane15 = lane & 15;
    const unsigned rsw   = (lane15 & 7) << 4;
    const unsigned kcol0 = (((lane >> 4) << 4)) ^ rsw;        // k elems 0..31
    const unsigned kcol1 = (64u + ((lane >> 4) << 4)) ^ rsw;  // k elems 32..63
    const unsigned smemBase =
        (unsigned)(size_t)(__attribute__((address_space(3))) char*)smem;
    const unsigned aB0 = smemBase + wr * 16384 + lane15 * 128;
    const unsigned bB0 = smemBase + 32768 + (wc >> 1) * 16384 +
                         ((wc & 1) * 64 + lane15) * 128;

    f32x4 acc[8][4];
#pragma unroll
    for (int m = 0; m < 8; m++)
#pragma unroll
        for (int n = 0; n < 4; n++) acc[m][n] = (f32x4){0.f, 0.f, 0.f, 0.f};

    STAGE2(A, lda, bmRow,       scol, 0);
    STAGE2(A, lda, bmRow + 128, scol, 16384);
    STAGE2(B, ldb, bnRow,       scol, 32768);
    STAGE2(B, ldb, bnRow + 128, scol, 49152);

    short8 afk0[4], afk1[4], bA0[2], bA1[2], bH0[2], bH1[2];

    for (int kt = 0; kt < nkt; ++kt) {
        const int c  = kt & 1;
        const bool pf = (kt + 1) < nkt;
        const int kc = (kt + 1) * 64 + scol;
        const unsigned aBase = aB0 + c * 65536;
        const unsigned bBase = bB0 + c * 65536;
        const unsigned lOff  = (c ^ 1) * 65536;

        // phase 0 : Q0
        if (pf) {
            STAGE2(A, lda, bmRow, kc, lOff);
            asm volatile("s_waitcnt vmcnt(2)" ::: "memory");
        } else {
            asm volatile("s_waitcnt vmcnt(0)" ::: "memory");
        }
        __builtin_amdgcn_s_barrier();
#pragma unroll
        for (int mf = 0; mf < 4; ++mf) {
            afk0[mf] = dsr128(aBase + mf * 2048 + kcol0);
            afk1[mf] = dsr128(aBase + mf * 2048 + kcol1);
        }
#pragma unroll
        for (int nf = 0; nf < 2; ++nf) {
            bA0[nf] = dsr128(bBase + nf * 2048 + kcol0);
            bA1[nf] = dsr128(bBase + nf * 2048 + kcol1);
        }
        asm volatile("s_waitcnt lgkmcnt(0)" ::: "memory");
        __builtin_amdgcn_sched_barrier(0);
        __builtin_amdgcn_s_setprio(1);
#pragma unroll
        for (int mf = 0; mf < 4; ++mf)
#pragma unroll
            for (int nf = 0; nf < 2; ++nf) {
                acc[mf][nf] = mfma16(bA0[nf], afk0[mf], acc[mf][nf]);
                acc[mf][nf] = mfma16(bA1[nf], afk1[mf], acc[mf][nf]);
            }
        __builtin_amdgcn_s_setprio(0);
        __builtin_amdgcn_s_barrier();

        // phase 1 : Q1
#pragma unroll
        for (int nf = 0; nf < 2; ++nf) {
            bH0[nf] = dsr128(bBase + (2 + nf) * 2048 + kcol0);
            bH1[nf] = dsr128(bBase + (2 + nf) * 2048 + kcol1);
        }
        if (pf) STAGE2(A, lda, bmRow + 128, kc, lOff + 16384);
        __builtin_amdgcn_s_barrier();
        asm volatile("s_waitcnt lgkmcnt(0)" ::: "memory");
        __builtin_amdgcn_sched_barrier(0);
        __builtin_amdgcn_s_setprio(1);
#pragma unroll
        for (int mf = 0; mf < 4; ++mf)
#pragma unroll
            for (int nf = 0; nf < 2; ++nf) {
                acc[mf][2 + nf] = mfma16(bH0[nf], afk0[mf], acc[mf][2 + nf]);
                acc[mf][2 + nf] = mfma16(bH1[nf], afk1[mf], acc[mf][2 + nf]);
            }
        __builtin_amdgcn_s_setprio(0);
        __builtin_amdgcn_s_barrier();

        // phase 2 : Q2
#pragma unroll
        for (int mf = 0; mf < 4; ++mf) {
            afk0[mf] = dsr128(aBase + (4 + mf) * 2048 + kcol0);
            afk1[mf] = dsr128(aBase + (4 + mf) * 2048 + kcol1);
        }
        if (pf) STAGE2(B, ldb, bnRow, kc, lOff + 32768);
        __builtin_amdgcn_s_barrier();
        asm volatile("s_waitcnt lgkmcnt(0)" ::: "memory");
        __builtin_amdgcn_sched_barrier(0);
        __builtin_amdgcn_s_setprio(1);
#pragma unroll
        for (int mf = 0; mf < 4; ++mf)
#pragma unroll
            for (int nf = 0; nf < 2; ++nf) {
                acc[4 + mf][2 + nf] = mfma16(bH0[nf], afk0[mf], acc[4 + mf][2 + nf]);
                acc[4 + mf][2 + nf] = mfma16(bH1[nf], afk1[mf], acc[4 + mf][2 + nf]);
            }
        __builtin_amdgcn_s_setprio(0);
        __builtin_amdgcn_s_barrier();

        // phase 3 : Q3
#pragma unroll
        for (int nf = 0; nf < 2; ++nf) {
            bA0[nf] = dsr128(bBase + nf * 2048 + kcol0);
            bA1[nf] = dsr128(bBase + nf * 2048 + kcol1);
        }
        if (pf) STAGE2(B, ldb, bnRow + 128, kc, lOff + 49152);
        __builtin_amdgcn_s_barrier();
        asm volatile("s_waitcnt lgkmcnt(0)" ::: "memory");
        __builtin_amdgcn_sched_barrier(0);
        __builtin_amdgcn_s_setprio(1);
#pragma unroll
        for (int mf = 0; mf < 4; ++mf)
#pragma unroll
            for (int nf = 0; nf < 2; ++nf) {
                acc[4 + mf][nf] = mfma16(bA0[nf], afk0[mf], acc[4 + mf][nf]);
                acc[4 + mf][nf] = mfma16(bA1[nf], afk1[mf], acc[4 + mf][nf]);
            }
        __builtin_amdgcn_s_setprio(0);
        __builtin_amdgcn_s_barrier();
    }

    const int cb4 = (lane >> 4) << 2;
    if (isHead) {
#pragma unroll
        for (int mf = 0; mf < 8; ++mf) {
            const long grow = bmRow + wr * 128 + mf * 16 + lane15;
            float* rp = C0 + grow * LDC;
#pragma unroll
            for (int nf = 0; nf < 4; ++nf) {
                const int gcb = (int)bnRow + wc * 64 + nf * 16 + cb4;
                f32x4 v = acc[mf][nf];
                if (gcb + 3 < width) {
                    __builtin_memcpy(rp + gcb, &v, 16);
                } else {
#pragma unroll
                    for (int j = 0; j < 4; ++j)
                        if (gcb + j < width) rp[gcb + j] = v[j];
                }
            }
        }
    } else {
#pragma unroll
        for (int mf = 0; mf < 8; ++mf) {
            const long grow = bmRow + wr * 128 + mf * 16 + lane15;
            unsigned short* rp = C1 + grow * ldc1;
#pragma unroll
            for (int nf = 0; nf < 4; ++nf) {
                const int gcb = (int)bnRow + wc * 64 + nf * 16 + cb4;
                const f32x4 v = acc[mf][nf];
                ushort4 o;
                o.x = f2bf(v[0]); o.y = f2bf(v[1]); o.z = f2bf(v[2]); o.w = f2bf(v[3]);
                if (gcb + 3 < width) {
                    *(ushort4*)(rp + gcb) = o;
                } else {
                    unsigned short tmp[4] = {o.x, o.y, o.z, o.w};
#pragma unroll
                    for (int j = 0; j < 4; ++j)
                        if (gcb + j < width) rp[gcb + j] = tmp[j];
                }
            }
        }
    }

    // ---- zero-fill of masked tail rows, sliced across all blocks ----
    {
        const int zc0 = 4096 - cnts[0];
        const int zc1 = 4096 - cnts[1];
        const f32x4 zv = {0.f, 0.f, 0.f, 0.f};
        for (int s = blockIdx.x; s < 8192; s += (int)gridDim.x) {
            const bool t0 = s < 4096;
            const int i = t0 ? s : s - 4096;
            if (i >= (t0 ? zc0 : zc1)) continue;
            const int rr = (t0 ? z0 : z1)[i];
            float* base = outFull + (long)rr * LDC + (t0 ? 10002 : 40002);
            const int n = t0 ? 30000 : 10257;
            for (int j = tid * 4; j <= n - 4; j += 2048)
                __builtin_memcpy(base + j, &zv, 16);
            for (int j = (n & ~3) + tid; j < n; j += 512)
                base[j] = 0.f;
        }
    }
}

// ===========================================================================
// L3: compacted tails, m97-128^2 dual-config (unchanged from R5).
// ===========================================================================
__global__ __launch_bounds__(256)
void gemm_tails_kernel(const unsigned short* __restrict__ A0,
                       const unsigned short* __restrict__ B0,
                       float* __restrict__ C0,
                       int K0, int lda0, int width0, int NB0, int nblk0,
                       const unsigned short* __restrict__ A1,
                       const unsigned short* __restrict__ B1,
                       float* __restrict__ C1,
                       int K1, int lda1, int width1, int NB1,
                       const int* __restrict__ in0,
                       const int* __restrict__ in1,
                       const int* __restrict__ cnts) {
    __shared__ unsigned short As[128 * 32];
    __shared__ unsigned short Bs[128 * 32];

    const int tid  = threadIdx.x;
    const int lane = tid & 63;
    const int wave = tid >> 6;
    const int wr   = wave >> 1;
    const int wc   = wave & 1;

    const bool is0 = (int)blockIdx.x < nblk0;
    const unsigned short* A = is0 ? A0 : A1;
    const unsigned short* B = is0 ? B0 : B1;
    float* Cf               = is0 ? C0 : C1;
    const int* rowlist      = is0 ? in0 : in1;
    const int cnt           = cnts[is0 ? 0 : 1];
    const int K     = is0 ? K0 : K1;
    const int lda   = is0 ? lda0 : lda1;
    const int width = is0 ? width0 : width1;
    const int NB    = is0 ? NB0 : NB1;
    const int lbid  = is0 ? blockIdx.x : blockIdx.x - nblk0;
    const int nwg   = is0 ? nblk0 : (int)gridDim.x - nblk0;

    const int q = nwg >> 3, r = nwg & 7;
    const int xcd = lbid & 7, loc = lbid >> 3;
    const int L = (xcd < r ? xcd * (q + 1) : r * (q + 1) + (xcd - r) * q) + loc;
    const int g = L / (NB << 3);
    const int t = L - g * (NB << 3);
    const long bm = (g << 3) + (t & 7);
    const long bn = t >> 3;

    if ((int)(bm * 128) >= cnt) return;

    const int cm1 = cnt - 1;
    const int s_row = tid >> 2;
    const int s_col = (tid & 3) << 3;
    const int gi0 = (int)(bm * 128) + s_row;
    const int gi1 = gi0 + 64;
    const int r0 = rowlist[gi0 < cnt ? gi0 : cm1];
    const int r1 = rowlist[gi1 < cnt ? gi1 : cm1];

    const unsigned short* pA0 = A + (long)r0 * lda + s_col;
    const unsigned short* pA1 = A + (long)r1 * lda + s_col;
    const unsigned short* pB  = B + (bn * 128 + s_row) * (long)K + s_col;

    char* asb = (char*)As + wave * 1024;
    char* bsb = (char*)Bs + wave * 1024;

    f32x4 acc[4][4];
#pragma unroll
    for (int m = 0; m < 4; m++)
#pragma unroll
        for (int n = 0; n < 4; n++) acc[m][n] = (f32x4){0.f, 0.f, 0.f, 0.f};

    const int f_r = lane & 15;
    const int f_k = (lane >> 4) << 3;

    for (int k0 = 0; k0 < K; k0 += 32) {
        gload16(pA0 + k0,          asb);
        gload16(pA1 + k0,          asb + 4096);
        gload16(pB + k0,           bsb);
        gload16(pB + k0 + 64L * K, bsb + 4096);
        __syncthreads();

        short8 af[4], bfr[4];
#pragma unroll
        for (int m = 0; m < 4; m++)
            af[m] = *(const short8*)&As[(wr * 64 + m * 16 + f_r) * 32 + f_k];
#pragma unroll
        for (int n = 0; n < 4; n++)
            bfr[n] = *(const short8*)&Bs[(wc * 64 + n * 16 + f_r) * 32 + f_k];

#pragma unroll
        for (int m = 0; m < 4; m++)
#pragma unroll
            for (int n = 0; n < 4; n++)
                acc[m][n] = __builtin_amdgcn_mfma_f32_16x16x32_bf16(
                    bfr[n], af[m], acc[m][n], 0, 0, 0);
        __syncthreads();
    }

    const int c_a  = lane & 15;
    const int c_b4 = (lane >> 4) << 2;
#pragma unroll
    for (int m = 0; m < 4; m++) {
        const int gri = (int)(bm * 128) + wr * 64 + m * 16 + c_a;
        if (gri < cnt) {
            const long orow = rowlist[gri];
            float* rp = Cf + orow * LDC;
#pragma unroll
            for (int n = 0; n < 4; n++) {
                const int gcb = (int)(bn * 128) + wc * 64 + n * 16 + c_b4;
                f32x4 v = acc[m][n];
                if (gcb + 3 < width) {
                    __builtin_memcpy(rp + gcb, &v, 16);
                } else {
#pragma unroll
                    for (int j = 0; j < 4; j++)
                        if (gcb + j < width) rp[gcb + j] = v[j];
                }
            }
        }
    }
}

extern "C" void kernel_launch(void* const* d_in, const int* in_sizes, int n_in,
                              void* d_out, int out_size, void* d_ws, size_t ws_size,
                              hipStream_t stream) {
    const float* x      = (const float*)d_in[0];   // [4096,1024]
    const int*   target = (const int*)  d_in[1];   // [4096]
    const float* head_w = (const float*)d_in[2];   // [10002,1024]
    const float* t0_w1  = (const float*)d_in[3];   // [256,1024]
    const float* t0_w2  = (const float*)d_in[4];   // [30000,256]
    const float* t1_w1  = (const float*)d_in[5];   // [64,1024]
    const float* t1_w2  = (const float*)d_in[6];   // [10257,64]
    float* out = (float*)d_out;

    // ---- ws layout (bytes) ----
    char* ws = (char*)d_ws;
    unsigned short* xb    = (unsigned short*)(ws + 0);          // 4096x1024
    unsigned short* hwb   = (unsigned short*)(ws + 8388608);    // 10240x1024
    unsigned short* w01b  = (unsigned short*)(ws + 29360128);   // 512x1024 (t0w1|t1w1|0)
    unsigned short* t0w2b = (unsigned short*)(ws + 30408704);   // 30208x256
    unsigned short* t1w2b = (unsigned short*)(ws + 45875200);   // 10496x64
    unsigned short* h01   = (unsigned short*)(ws + 47218688);   // 4096x384 bf16
    int*            in0   = (int*)(ws + 50364416);              // 4096
    int*            z0l   = (int*)(ws + 50380800);              // 4096
    int*            in1   = (int*)(ws + 50397184);              // 4096
    int*            z1l   = (int*)(ws + 50413568);              // 4096
    int*            cnts  = (int*)(ws + 50429952);              // 2

    // ---- L0: scan (target remap + compaction lists) ----
    scan_kernel<<<1, 1024, 0, stream>>>(target, out + 4096L * LDC,
                                        in0, z0l, in1, z1l, cnts);

    // ---- L1: casts only ----
    CastArgs ca;
    ca.s[0] = {x,      nullptr, xb,    4096,  4096,  524288,  10, 0};
    ca.s[1] = {head_w, nullptr, hwb,   10002, 10002, 1310720, 10, 0};
    ca.s[2] = {t0_w1,  t1_w1,   w01b,  256,   320,   65536,   10, 0};
    ca.s[3] = {t0_w2,  nullptr, t0w2b, 30000, 30000, 966656,  8,  0};
    ca.s[4] = {t1_w2,  nullptr, t1w2b, 10257, 10257, 83968,   6,  0};
    ca.grand8 = 524288 + 1310720 + 65536 + 966656 + 83968;  // 2951168
    cast_kernel<<<2048, 256, 0, stream>>>(ca);

    // ---- L2: head (640 blocks, 8-phase) + h01 (32 blocks) + zero-fill ----
    gemm8_dual_kernel<<<dim3(672), 512, 0, stream>>>(
        xb, hwb, out, 16, 1024, 1024, 10002, 40, 640,
        xb, w01b, h01, 16, 1024, 1024, 384L, 384, 2,
        z0l, z1l, cnts, out);

    // ---- L3: compacted tails (worst-case grid, early-exit by cnt) ----
    gemm_tails_kernel<<<dim3(10112), 256, 0, stream>>>(
        h01,       t0w2b, out + 10002, 256, 384, 30000, 235, 7520,
        h01 + 256, t1w2b, out + 40002, 64,  384, 10257, 81,
        in0, in1, cnts);
}

// Round 7
// 374.658 us; speedup vs baseline: 1.1167x; 1.1167x over previous
//
#include <hip/hip_runtime.h>
#include <hip/hip_bf16.h>
#include <stdint.h>

// ---------------------------------------------------------------------------
// FacebookAdaptiveSoftmax forward on MI355X (gfx950) — R7
//   out[4096, 50259] = concat(x@head_w^T, (x@t0w1^T)@t0w2^T * m0, (x@t1w1^T)@t1w2^T * m1)
//   new_head_target[4096] appended flat (as float)
// R7 changes vs R6:
//   * Coalesced C-stores: both GEMM epilogues transpose acc through LDS
//     (slot^(row&7) swizzle) so each wave-inst stores one contiguous run in
//     ONE row (1KB head / 512B tails) instead of 16 rows x 64B page-scatter.
//   * Zero-fill of masked tail rows moved to L3's idle (early-exit) blocks,
//     overlapping the staging-latency-bound tail GEMMs. L2 is pure GEMM.
// ---------------------------------------------------------------------------

typedef float  f32x4   __attribute__((ext_vector_type(4)));
typedef short  short8  __attribute__((ext_vector_type(8)));
typedef unsigned short ushort8 __attribute__((ext_vector_type(8)));

#define CUT0 10000
#define CUT1 40000
#define CUT2 50257
#define LDC   50259L

__device__ __forceinline__ void gload16(const void* g, void* l) {
    __builtin_amdgcn_global_load_lds(
        (__attribute__((address_space(1))) void*)(g),
        (__attribute__((address_space(3))) void*)(l), 16, 0, 0);
}

__device__ __forceinline__ unsigned short f2bf(float f) {
    unsigned int u = __float_as_uint(f);
    u += 0x7fffu + ((u >> 16) & 1u);   // round-to-nearest-even
    return (unsigned short)(u >> 16);
}

__device__ __forceinline__ short8 dsr128(unsigned addr) {
    f32x4 r;
    asm volatile("ds_read_b128 %0, %1" : "=v"(r) : "v"(addr));
    return __builtin_bit_cast(short8, r);
}

__device__ __forceinline__ f32x4 mfma16(short8 a, short8 b, f32x4 c) {
    return __builtin_amdgcn_mfma_f32_16x16x32_bf16(a, b, c, 0, 0, 0);
}

// ===========================================================================
// L0: target remap + order-preserving compaction scan (1 block, 1024 thr).
// ===========================================================================
__global__ __launch_bounds__(1024)
void scan_kernel(const int* __restrict__ tgt, float* __restrict__ outT,
                 int* __restrict__ in0, int* __restrict__ z0,
                 int* __restrict__ in1, int* __restrict__ z1,
                 int* __restrict__ cnts) {
    __shared__ int w0[16], w1[16];
    const int t = threadIdx.x;
    int f0[4], f1[4];
    int c0 = 0, c1 = 0;
#pragma unroll
    for (int j = 0; j < 4; ++j) {
        const int r = t * 4 + j;
        const int v = tgt[r];
        const int b0 = (v >= CUT0) && (v < CUT1);
        const int b1 = (v >= CUT1) && (v < CUT2);
        f0[j] = b0; f1[j] = b1;
        c0 += b0; c1 += b1;
        outT[r] = (float)(b0 ? CUT0 : (b1 ? CUT0 + 1 : v));
    }
    const int lane = t & 63, w = t >> 6;
    int s0 = c0, s1 = c1;
    for (int d = 1; d < 64; d <<= 1) {
        const int u0 = __shfl_up(s0, d, 64);
        const int u1 = __shfl_up(s1, d, 64);
        if (lane >= d) { s0 += u0; s1 += u1; }
    }
    if (lane == 63) { w0[w] = s0; w1[w] = s1; }
    __syncthreads();
    if (t == 0) {
        int a0 = 0, a1 = 0;
        for (int i = 0; i < 16; ++i) {
            const int x0 = w0[i]; w0[i] = a0; a0 += x0;
            const int x1 = w1[i]; w1[i] = a1; a1 += x1;
        }
        cnts[0] = a0; cnts[1] = a1;
    }
    __syncthreads();
    int run0 = w0[w] + (s0 - c0);
    int run1 = w1[w] + (s1 - c1);
#pragma unroll
    for (int j = 0; j < 4; ++j) {
        const int r = t * 4 + j;
        if (f0[j]) in0[run0++] = r; else z0[r - run0] = r;
        if (f1[j]) in1[run1++] = r; else z1[r - run1] = r;
    }
}

// ===========================================================================
// L1: fused casts only (5 segments, f32 -> bf16, zero row padding).
// ===========================================================================
struct CastSeg {
    const float* srcA;
    const float* srcB;
    unsigned short* dst;
    long rowsA, rowsB, total8;
    int lk, pad;
};
struct CastArgs {
    CastSeg s[5];
    long grand8;
};

__global__ __launch_bounds__(256)
void cast_kernel(CastArgs a) {
    long i = blockIdx.x * 256L + threadIdx.x;
    const long stride = (long)gridDim.x * 256L;
    for (; i < a.grand8; i += stride) {
        long off = i;
        int s = 0;
        while (s < 4 && off >= a.s[s].total8) { off -= a.s[s].total8; s++; }
        const CastSeg& sg = a.s[s];
        const long e   = off << 3;
        const long row = e >> sg.lk;
        ushort8 o;
        const float* src = nullptr;
        long r2 = row;
        if (row < sg.rowsA)      src = sg.srcA;
        else if (row < sg.rowsB) { src = sg.srcB; r2 = row - sg.rowsA; }
        if (src) {
            const long col = e & ((1L << sg.lk) - 1);
            const float* p = src + (r2 << sg.lk) + col;
            const float4 v0 = *(const float4*)(p);
            const float4 v1 = *(const float4*)(p + 4);
            o[0] = f2bf(v0.x); o[1] = f2bf(v0.y); o[2] = f2bf(v0.z); o[3] = f2bf(v0.w);
            o[4] = f2bf(v1.x); o[5] = f2bf(v1.y); o[6] = f2bf(v1.z); o[7] = f2bf(v1.w);
        } else {
            o = (ushort8)0;
        }
        *(ushort8*)(sg.dst + e) = o;
    }
}

// ===========================================================================
// L2: 8-phase 256x256 BK=64 GEMM, dual-config (head f32-out | h01 bf16-out).
// Head epilogue: LDS-transposed coalesced stores (1KB contiguous per
// wave-inst, one row each). (row&7)-swizzled K-tile LDS from R6 retained.
// ===========================================================================
#define STAGE2(MATP, LDM, RB, KCOL, LOFF)                                          \
    do {                                                                           \
        const unsigned short* _s0 = (MATP) + ((long)((RB) + (tid >> 3))) * (LDM) + (KCOL); \
        gload16(_s0, smem + (LOFF) + wave * 1024);                                 \
        const unsigned short* _s1 = (MATP) + ((long)((RB) + 64 + (tid >> 3))) * (LDM) + (KCOL); \
        gload16(_s1, smem + (LOFF) + 8192 + wave * 1024);                          \
    } while (0)

__global__ __launch_bounds__(512, 2)
void gemm8_dual_kernel(const unsigned short* __restrict__ A0,
                       const unsigned short* __restrict__ B0,
                       float* __restrict__ C0,
                       int nkt0, int lda0, int ldb0, int width0, int NB0, int nblk0,
                       const unsigned short* __restrict__ A1,
                       const unsigned short* __restrict__ B1,
                       unsigned short* __restrict__ C1,
                       int nkt1, int lda1, int ldb1, long ldc1, int width1, int NB1) {
    __shared__ char smem[131072];

    const int tid  = threadIdx.x;
    const int lane = tid & 63;
    const int wave = tid >> 6;
    const int wr   = wave >> 2;
    const int wc   = wave & 3;

    const bool isHead = (int)blockIdx.x < nblk0;
    const unsigned short* A = isHead ? A0 : A1;
    const unsigned short* B = isHead ? B0 : B1;
    const int nkt   = isHead ? nkt0 : nkt1;
    const int lda   = isHead ? lda0 : lda1;
    const int ldb   = isHead ? ldb0 : ldb1;
    const int width = isHead ? width0 : width1;
    const int NB    = isHead ? NB0 : NB1;
    const int lbid  = isHead ? blockIdx.x : blockIdx.x - nblk0;
    const int nwg   = isHead ? nblk0 : (int)gridDim.x - nblk0;

    const int q = nwg >> 3, r = nwg & 7;
    const int xcd = lbid & 7, loc = lbid >> 3;
    const int L = (xcd < r ? xcd * (q + 1) : r * (q + 1) + (xcd - r) * q) + loc;
    const int g = L / (NB * 4);
    const int t = L - g * (NB * 4);
    const long bm = g * 4 + (t & 3);
    const long bn = t >> 2;

    const long bmRow = bm * 256;
    const long bnRow = bn * 256;

    // staging source slot pre-swizzled by row&7: slot_src = (tid&7) ^ (row&7)
    const int scol = (((tid & 7) ^ ((tid >> 3) & 7)) << 3);

    // ds_read addresses: byte col = kbyte ^ ((row&7)<<4), row = lane&15
    const unsigned lane15 = lane & 15;
    const unsigned rsw   = (lane15 & 7) << 4;
    const unsigned kcol0 = (((lane >> 4) << 4)) ^ rsw;
    const unsigned kcol1 = (64u + ((lane >> 4) << 4)) ^ rsw;
    const unsigned smemBase =
        (unsigned)(size_t)(__attribute__((address_space(3))) char*)smem;
    const unsigned aB0 = smemBase + wr * 16384 + lane15 * 128;
    const unsigned bB0 = smemBase + 32768 + (wc >> 1) * 16384 +
                         ((wc & 1) * 64 + lane15) * 128;

    f32x4 acc[8][4];
#pragma unroll
    for (int m = 0; m < 8; m++)
#pragma unroll
        for (int n = 0; n < 4; n++) acc[m][n] = (f32x4){0.f, 0.f, 0.f, 0.f};

    STAGE2(A, lda, bmRow,       scol, 0);
    STAGE2(A, lda, bmRow + 128, scol, 16384);
    STAGE2(B, ldb, bnRow,       scol, 32768);
    STAGE2(B, ldb, bnRow + 128, scol, 49152);

    short8 afk0[4], afk1[4], bA0[2], bA1[2], bH0[2], bH1[2];

    for (int kt = 0; kt < nkt; ++kt) {
        const int c  = kt & 1;
        const bool pf = (kt + 1) < nkt;
        const int kc = (kt + 1) * 64 + scol;
        const unsigned aBase = aB0 + c * 65536;
        const unsigned bBase = bB0 + c * 65536;
        const unsigned lOff  = (c ^ 1) * 65536;

        // phase 0 : Q0
        if (pf) {
            STAGE2(A, lda, bmRow, kc, lOff);
            asm volatile("s_waitcnt vmcnt(2)" ::: "memory");
        } else {
            asm volatile("s_waitcnt vmcnt(0)" ::: "memory");
        }
        __builtin_amdgcn_s_barrier();
#pragma unroll
        for (int mf = 0; mf < 4; ++mf) {
            afk0[mf] = dsr128(aBase + mf * 2048 + kcol0);
            afk1[mf] = dsr128(aBase + mf * 2048 + kcol1);
        }
#pragma unroll
        for (int nf = 0; nf < 2; ++nf) {
            bA0[nf] = dsr128(bBase + nf * 2048 + kcol0);
            bA1[nf] = dsr128(bBase + nf * 2048 + kcol1);
        }
        asm volatile("s_waitcnt lgkmcnt(0)" ::: "memory");
        __builtin_amdgcn_sched_barrier(0);
        __builtin_amdgcn_s_setprio(1);
#pragma unroll
        for (int mf = 0; mf < 4; ++mf)
#pragma unroll
            for (int nf = 0; nf < 2; ++nf) {
                acc[mf][nf] = mfma16(bA0[nf], afk0[mf], acc[mf][nf]);
                acc[mf][nf] = mfma16(bA1[nf], afk1[mf], acc[mf][nf]);
            }
        __builtin_amdgcn_s_setprio(0);
        __builtin_amdgcn_s_barrier();

        // phase 1 : Q1
#pragma unroll
        for (int nf = 0; nf < 2; ++nf) {
            bH0[nf] = dsr128(bBase + (2 + nf) * 2048 + kcol0);
            bH1[nf] = dsr128(bBase + (2 + nf) * 2048 + kcol1);
        }
        if (pf) STAGE2(A, lda, bmRow + 128, kc, lOff + 16384);
        __builtin_amdgcn_s_barrier();
        asm volatile("s_waitcnt lgkmcnt(0)" ::: "memory");
        __builtin_amdgcn_sched_barrier(0);
        __builtin_amdgcn_s_setprio(1);
#pragma unroll
        for (int mf = 0; mf < 4; ++mf)
#pragma unroll
            for (int nf = 0; nf < 2; ++nf) {
                acc[mf][2 + nf] = mfma16(bH0[nf], afk0[mf], acc[mf][2 + nf]);
                acc[mf][2 + nf] = mfma16(bH1[nf], afk1[mf], acc[mf][2 + nf]);
            }
        __builtin_amdgcn_s_setprio(0);
        __builtin_amdgcn_s_barrier();

        // phase 2 : Q2
#pragma unroll
        for (int mf = 0; mf < 4; ++mf) {
            afk0[mf] = dsr128(aBase + (4 + mf) * 2048 + kcol0);
            afk1[mf] = dsr128(aBase + (4 + mf) * 2048 + kcol1);
        }
        if (pf) STAGE2(B, ldb, bnRow, kc, lOff + 32768);
        __builtin_amdgcn_s_barrier();
        asm volatile("s_waitcnt lgkmcnt(0)" ::: "memory");
        __builtin_amdgcn_sched_barrier(0);
        __builtin_amdgcn_s_setprio(1);
#pragma unroll
        for (int mf = 0; mf < 4; ++mf)
#pragma unroll
            for (int nf = 0; nf < 2; ++nf) {
                acc[4 + mf][2 + nf] = mfma16(bH0[nf], afk0[mf], acc[4 + mf][2 + nf]);
                acc[4 + mf][2 + nf] = mfma16(bH1[nf], afk1[mf], acc[4 + mf][2 + nf]);
            }
        __builtin_amdgcn_s_setprio(0);
        __builtin_amdgcn_s_barrier();

        // phase 3 : Q3
#pragma unroll
        for (int nf = 0; nf < 2; ++nf) {
            bA0[nf] = dsr128(bBase + nf * 2048 + kcol0);
            bA1[nf] = dsr128(bBase + nf * 2048 + kcol1);
        }
        if (pf) STAGE2(B, ldb, bnRow + 128, kc, lOff + 49152);
        __builtin_amdgcn_s_barrier();
        asm volatile("s_waitcnt lgkmcnt(0)" ::: "memory");
        __builtin_amdgcn_sched_barrier(0);
        __builtin_amdgcn_s_setprio(1);
#pragma unroll
        for (int mf = 0; mf < 4; ++mf)
#pragma unroll
            for (int nf = 0; nf < 2; ++nf) {
                acc[4 + mf][nf] = mfma16(bA0[nf], afk0[mf], acc[4 + mf][nf]);
                acc[4 + mf][nf] = mfma16(bA1[nf], afk1[mf], acc[4 + mf][nf]);
            }
        __builtin_amdgcn_s_setprio(0);
        __builtin_amdgcn_s_barrier();
    }

    const int cb4 = (lane >> 4) << 2;
    if (isHead) {
        // ---- transposed coalesced epilogue: LDS [128][256] f32, 2 passes ----
        for (int h = 0; h < 2; ++h) {
            __syncthreads();
            if (wr == h) {
#pragma unroll
                for (int mf = 0; mf < 8; ++mf) {
                    const int rl = mf * 16 + (int)lane15;
#pragma unroll
                    for (int nf = 0; nf < 4; ++nf) {
                        const int slot = wc * 16 + nf * 4 + (lane >> 4);
                        const int sl = slot ^ (rl & 7);
                        *(f32x4*)(smem + rl * 1024 + sl * 16) = acc[mf][nf];
                    }
                }
            }
            __syncthreads();
            const int colBase = (int)bnRow + lane * 4;
#pragma unroll
            for (int it = 0; it < 16; ++it) {
                const int rl = wave * 16 + it;
                const int sl = lane ^ (rl & 7);
                const f32x4 v = *(const f32x4*)(smem + rl * 1024 + sl * 16);
                float* rp = C0 + (bmRow + h * 128 + rl) * LDC;
                if (colBase + 3 < width) {
                    __builtin_memcpy(rp + colBase, &v, 16);
                } else {
#pragma unroll
                    for (int j = 0; j < 4; ++j)
                        if (colBase + j < width) rp[colBase + j] = v[j];
                }
            }
        }
    } else {
#pragma unroll
        for (int mf = 0; mf < 8; ++mf) {
            const long grow = bmRow + wr * 128 + mf * 16 + lane15;
            unsigned short* rp = C1 + grow * ldc1;
#pragma unroll
            for (int nf = 0; nf < 4; ++nf) {
                const int gcb = (int)bnRow + wc * 64 + nf * 16 + cb4;
                const f32x4 v = acc[mf][nf];
                ushort4 o;
                o.x = f2bf(v[0]); o.y = f2bf(v[1]); o.z = f2bf(v[2]); o.w = f2bf(v[3]);
                if (gcb + 3 < width) {
                    *(ushort4*)(rp + gcb) = o;
                } else {
                    unsigned short tmp[4] = {o.x, o.y, o.z, o.w};
#pragma unroll
                    for (int j = 0; j < 4; ++j)
                        if (gcb + j < width) rp[gcb + j] = tmp[j];
                }
            }
        }
    }
}

// ===========================================================================
// L3: compacted tails, m97-128^2 dual-config, transposed coalesced epilogue
// (LDS [64][128] f32 union over As/Bs, 2 passes, 512B runs). Idle blocks and
// finished blocks zero-fill masked tail rows (strided, deterministic).
// ===========================================================================
__global__ __launch_bounds__(256)
void gemm_tails_kernel(const unsigned short* __restrict__ A0,
                       const unsigned short* __restrict__ B0,
                       float* __restrict__ C0,
                       int K0, int lda0, int width0, int NB0, int nblk0,
                       const unsigned short* __restrict__ A1,
                       const unsigned short* __restrict__ B1,
                       float* __restrict__ C1,
                       int K1, int lda1, int width1, int NB1,
                       const int* __restrict__ in0,
                       const int* __restrict__ in1,
                       const int* __restrict__ z0,
                       const int* __restrict__ z1,
                       const int* __restrict__ cnts) {
    __shared__ char tsm[32768];
    unsigned short* As = (unsigned short*)tsm;
    unsigned short* Bs = (unsigned short*)(tsm + 8192);

    const int tid  = threadIdx.x;
    const int lane = tid & 63;
    const int wave = tid >> 6;
    const int wr   = wave >> 1;
    const int wc   = wave & 1;

    const bool is0 = (int)blockIdx.x < nblk0;
    const unsigned short* A = is0 ? A0 : A1;
    const unsigned short* B = is0 ? B0 : B1;
    float* Cf               = is0 ? C0 : C1;
    const int* rowlist      = is0 ? in0 : in1;
    const int cnt           = cnts[is0 ? 0 : 1];
    const int K     = is0 ? K0 : K1;
    const int lda   = is0 ? lda0 : lda1;
    const int width = is0 ? width0 : width1;
    const int NB    = is0 ? NB0 : NB1;
    const int lbid  = is0 ? blockIdx.x : blockIdx.x - nblk0;
    const int nwg   = is0 ? nblk0 : (int)gridDim.x - nblk0;

    const int q = nwg >> 3, r = nwg & 7;
    const int xcd = lbid & 7, loc = lbid >> 3;
    const int L = (xcd < r ? xcd * (q + 1) : r * (q + 1) + (xcd - r) * q) + loc;
    const int g = L / (NB << 3);
    const int t = L - g * (NB << 3);
    const long bm = (g << 3) + (t & 7);
    const long bn = t >> 3;

    const bool active = (int)(bm * 128) < cnt;

    if (active) {
        const int cm1 = cnt - 1;
        const int s_row = tid >> 2;
        const int s_col = (tid & 3) << 3;
        const int gi0 = (int)(bm * 128) + s_row;
        const int gi1 = gi0 + 64;
        const int r0 = rowlist[gi0 < cnt ? gi0 : cm1];
        const int r1 = rowlist[gi1 < cnt ? gi1 : cm1];

        const unsigned short* pA0 = A + (long)r0 * lda + s_col;
        const unsigned short* pA1 = A + (long)r1 * lda + s_col;
        const unsigned short* pB  = B + (bn * 128 + s_row) * (long)K + s_col;

        char* asb = (char*)As + wave * 1024;
        char* bsb = (char*)Bs + wave * 1024;

        f32x4 acc[4][4];
#pragma unroll
        for (int m = 0; m < 4; m++)
#pragma unroll
            for (int n = 0; n < 4; n++) acc[m][n] = (f32x4){0.f, 0.f, 0.f, 0.f};

        const int f_r = lane & 15;
        const int f_k = (lane >> 4) << 3;

        for (int k0 = 0; k0 < K; k0 += 32) {
            gload16(pA0 + k0,          asb);
            gload16(pA1 + k0,          asb + 4096);
            gload16(pB + k0,           bsb);
            gload16(pB + k0 + 64L * K, bsb + 4096);
            __syncthreads();

            short8 af[4], bfr[4];
#pragma unroll
            for (int m = 0; m < 4; m++)
                af[m] = *(const short8*)&As[(wr * 64 + m * 16 + f_r) * 32 + f_k];
#pragma unroll
            for (int n = 0; n < 4; n++)
                bfr[n] = *(const short8*)&Bs[(wc * 64 + n * 16 + f_r) * 32 + f_k];

#pragma unroll
            for (int m = 0; m < 4; m++)
#pragma unroll
                for (int n = 0; n < 4; n++)
                    acc[m][n] = __builtin_amdgcn_mfma_f32_16x16x32_bf16(
                        bfr[n], af[m], acc[m][n], 0, 0, 0);
            __syncthreads();
        }

        // ---- transposed coalesced epilogue: LDS [64][128] f32, 2 passes ----
        const int c_a  = lane & 15;
        const int colL = (lane & 31) * 4;
        for (int h = 0; h < 2; ++h) {
            __syncthreads();
            if (wr == h) {
#pragma unroll
                for (int m = 0; m < 4; ++m) {
                    const int rl = m * 16 + c_a;
#pragma unroll
                    for (int n = 0; n < 4; ++n) {
                        const int slot = wc * 16 + n * 4 + (lane >> 4);
                        const int sl = slot ^ (rl & 7);
                        *(f32x4*)(tsm + rl * 512 + sl * 16) = acc[m][n];
                    }
                }
            }
            __syncthreads();
#pragma unroll
            for (int it = 0; it < 8; ++it) {
                const int rl = wave * 16 + it * 2 + (lane >> 5);
                const int gri = (int)(bm * 128) + h * 64 + rl;
                if (gri < cnt) {
                    const int sl = (lane & 31) ^ (rl & 7);
                    const f32x4 v = *(const f32x4*)(tsm + rl * 512 + sl * 16);
                    const long orow = rowlist[gri];
                    float* rp = Cf + orow * LDC;
                    const int col = (int)(bn * 128) + colL;
                    if (col + 3 < width) {
                        __builtin_memcpy(rp + col, &v, 16);
                    } else {
#pragma unroll
                        for (int j = 0; j < 4; ++j)
                            if (col + j < width) rp[col + j] = v[j];
                    }
                }
            }
        }
    }

    // ---- zero-fill of masked tail rows (idle blocks start immediately) ----
    {
        const f32x4 zv = {0.f, 0.f, 0.f, 0.f};
        const int zc = 4096 - cnt;
        const int* zl = is0 ? z0 : z1;
        for (int s = lbid; s < zc; s += nwg) {
            const int rr = zl[s];
            float* base = Cf + (long)rr * LDC;
            for (int j = tid * 4; j + 3 < width; j += 1024)
                __builtin_memcpy(base + j, &zv, 16);
            for (int j = (width & ~3) + tid; j < width; j += 256)
                base[j] = 0.f;
        }
    }
}

extern "C" void kernel_launch(void* const* d_in, const int* in_sizes, int n_in,
                              void* d_out, int out_size, void* d_ws, size_t ws_size,
                              hipStream_t stream) {
    const float* x      = (const float*)d_in[0];   // [4096,1024]
    const int*   target = (const int*)  d_in[1];   // [4096]
    const float* head_w = (const float*)d_in[2];   // [10002,1024]
    const float* t0_w1  = (const float*)d_in[3];   // [256,1024]
    const float* t0_w2  = (const float*)d_in[4];   // [30000,256]
    const float* t1_w1  = (const float*)d_in[5];   // [64,1024]
    const float* t1_w2  = (const float*)d_in[6];   // [10257,64]
    float* out = (float*)d_out;

    // ---- ws layout (bytes) ----
    char* ws = (char*)d_ws;
    unsigned short* xb    = (unsigned short*)(ws + 0);          // 4096x1024
    unsigned short* hwb   = (unsigned short*)(ws + 8388608);    // 10240x1024
    unsigned short* w01b  = (unsigned short*)(ws + 29360128);   // 512x1024 (t0w1|t1w1|0)
    unsigned short* t0w2b = (unsigned short*)(ws + 30408704);   // 30208x256
    unsigned short* t1w2b = (unsigned short*)(ws + 45875200);   // 10496x64
    unsigned short* h01   = (unsigned short*)(ws + 47218688);   // 4096x384 bf16
    int*            in0   = (int*)(ws + 50364416);              // 4096
    int*            z0l   = (int*)(ws + 50380800);              // 4096
    int*            in1   = (int*)(ws + 50397184);              // 4096
    int*            z1l   = (int*)(ws + 50413568);              // 4096
    int*            cnts  = (int*)(ws + 50429952);              // 2

    // ---- L0: scan (target remap + compaction lists) ----
    scan_kernel<<<1, 1024, 0, stream>>>(target, out + 4096L * LDC,
                                        in0, z0l, in1, z1l, cnts);

    // ---- L1: casts only ----
    CastArgs ca;
    ca.s[0] = {x,      nullptr, xb,    4096,  4096,  524288,  10, 0};
    ca.s[1] = {head_w, nullptr, hwb,   10002, 10002, 1310720, 10, 0};
    ca.s[2] = {t0_w1,  t1_w1,   w01b,  256,   320,   65536,   10, 0};
    ca.s[3] = {t0_w2,  nullptr, t0w2b, 30000, 30000, 966656,  8,  0};
    ca.s[4] = {t1_w2,  nullptr, t1w2b, 10257, 10257, 83968,   6,  0};
    ca.grand8 = 524288 + 1310720 + 65536 + 966656 + 83968;  // 2951168
    cast_kernel<<<2048, 256, 0, stream>>>(ca);

    // ---- L2: head (640 blocks, 8-phase) + h01 (32 blocks) ----
    gemm8_dual_kernel<<<dim3(672), 512, 0, stream>>>(
        xb, hwb, out, 16, 1024, 1024, 10002, 40, 640,
        xb, w01b, h01, 16, 1024, 1024, 384L, 384, 2);

    // ---- L3: compacted tails + zero-fills (early-exit blocks fill) ----
    gemm_tails_kernel<<<dim3(10112), 256, 0, stream>>>(
        h01,       t0w2b, out + 10002, 256, 384, 30000, 235, 7520,
        h01 + 256, t1w2b, out + 40002, 64,  384, 10257, 81,
        in0, in1, z0l, z1l, cnts);
}